// Round 10
// baseline (166.501 us; speedup 1.0000x reference)
//
#include <hip/hip_runtime.h>
#include <hip/hip_bf16.h>

// Net: x(8) -> SKIP: y = (W11 x + b11)*(W21 x + b21)   (128)
//      -> MUL : y2 = (W12 y + b12)*(W22 y + b22)       (128)
//      -> out = wout . y2                              (scalar)
// grad = JVP with tangent xdot (== reference Jacobian chain . xdot).
//
// R9 postmortem: 44.7us with MfmaUtil 13 / occ 13.5% — LDS (64KB, 2 blk/CU)
// + barrier + 591K bank-conflict cycles spent transforming layer-1 C/D
// output into layer-2 A-frags. R10: pick layer-2's k-ORDER so the transform
// is the identity. GEMM k-sum is order-free; conv_w packs B (W12/W22) with
// k(kt,q,j) = 16kt+4q+j (j<4) | 64+16kt+4q+(j-4) (j>=4). Then lane (q,c)'s
// layer-1 products y[16ot+4q+r][c] ARE its layer-2 A-frag dwords for
// kt=ot (j<4) and kt=ot-4 (j>=4). Zero LDS / barrier / shuffle; occupancy
// now VGPR-bound (launch_bounds(256,4), cap 128; R9 measured 100).
//
// Layouts HW-verified R7-R9: A/B[idx=lane&15][slot j: dword d = (j=2d,2d+1),
// quad selects slot group], C/D col=lane&15, row=4q+r.
//
// d_ws layout (dwords): [0,8192) W12 k-permuted bf16-pairs; [8192,16384)
// W22 same; [16384,18432) W11 A-frags (ot*64+lane)*4; [18432,20480) W21.
//
// Outputs (fp32, concat): v_t[65536], v_y[65536], v_grad[65536], v_center[512]

#define NIN 8
#define H 128
#define BLK 256

typedef short short8 __attribute__((ext_vector_type(8)));
typedef float f32x4 __attribute__((ext_vector_type(4)));
typedef unsigned uint32x4 __attribute__((ext_vector_type(4)));

// fp32 -> bf16 RNE (finite only) — verified R6-R9
__device__ __forceinline__ unsigned bf16_bits(float f) {
    unsigned u = __float_as_uint(f);
    return (u + 0x7fffu + ((u >> 16) & 1u)) >> 16;
}
__device__ __forceinline__ unsigned pack_bf16(float a, float b) {
    return bf16_bits(a) | (bf16_bits(b) << 16);   // a = even element (low 16)
}
__device__ __forceinline__ short8 pack8(float4 a, float4 b) {
    uint4 u = make_uint4(pack_bf16(a.x, a.y), pack_bf16(a.z, a.w),
                         pack_bf16(b.x, b.y), pack_bf16(b.z, b.w));
    return __builtin_bit_cast(short8, u);
}

// Build weight structures in d_ws. B-side (W12/W22) uses the k-permutation
// that makes the layer-1->layer-2 fragment hand-off an identity.
__global__ __launch_bounds__(256, 1) void conv_w(
    const float* __restrict__ W12, const float* __restrict__ W22,
    const float* __restrict__ W11, const float* __restrict__ W21,
    unsigned* __restrict__ ws)
{
    int i = blockIdx.x * 256 + threadIdx.x;       // 0..8191
    int oc = i >> 6, rem = i & 63;
    int kt = rem >> 4, q = (rem >> 2) & 3, d = rem & 3;
    // dword d of frag (oc,kt,q): j = 2d,2d+1
    int base = (d < 2) ? (16 * kt + 4 * q + 2 * d)
                       : (64 + 16 * kt + 4 * q + 2 * (d - 2));
    const float* r12 = W12 + oc * H;
    const float* r22 = W22 + oc * H;
    ws[i]        = pack_bf16(r12[base], r12[base + 1]);
    ws[8192 + i] = pack_bf16(r22[base], r22[base + 1]);
    if (i < 512) {                                // layer-1 A-frags (R9-verified)
        int ot = i >> 6, lane = i & 63;
        int qq = lane >> 4, c = lane & 15;
        int o = 16 * ot + c;
        uint4 f1 = make_uint4(0, 0, 0, 0), f2 = make_uint4(0, 0, 0, 0);
        if (qq == 0) {                            // k=0..7 real, rest zero
            const float4* r1 = reinterpret_cast<const float4*>(W11 + o * NIN);
            const float4* r2 = reinterpret_cast<const float4*>(W21 + o * NIN);
            float4 x0 = r1[0], x1 = r1[1];
            f1 = make_uint4(pack_bf16(x0.x, x0.y), pack_bf16(x0.z, x0.w),
                            pack_bf16(x1.x, x1.y), pack_bf16(x1.z, x1.w));
            float4 y0 = r2[0], y1 = r2[1];
            f2 = make_uint4(pack_bf16(y0.x, y0.y), pack_bf16(y0.z, y0.w),
                            pack_bf16(y1.x, y1.y), pack_bf16(y1.z, y1.w));
        }
        *reinterpret_cast<uint4*>(ws + 16384 + i * 4) = f1;
        *reinterpret_cast<uint4*>(ws + 18432 + i * 4) = f2;
    }
}

// Blocks: [0,nCb) fwd(center,256); [nCb,nCb+nTb) fwd(T,256); rest grad(l,128).
// NO LDS, NO barrier — waves fully autonomous.
__global__ __launch_bounds__(BLK, 4) void net_kernel(
    const float* __restrict__ T, int nTb,
    const float* __restrict__ L, const float* __restrict__ Ld,
    const float* __restrict__ C, int nCb,
    const float* __restrict__ b11, const float* __restrict__ b21,
    const unsigned* __restrict__ wsb,
    const float* __restrict__ b12, const float* __restrict__ b22,
    const float* __restrict__ wout,
    float* __restrict__ outT, float* __restrict__ outY,
    float* __restrict__ outG, float* __restrict__ outC)
{
    const int tid  = threadIdx.x;
    const int wave = tid >> 6;
    const int lane = tid & 63;
    const int q    = lane >> 4;
    const int c    = lane & 15;

    const int bid = blockIdx.x;
    const bool is_grad = (bid >= nCb + nTb);

    const unsigned* w12p = wsb;
    const unsigned* w22p = wsb + 8192;
    const unsigned* wf1p = wsb + 16384 + (lane << 2);
    const unsigned* wf2p = wsb + 18432 + (lane << 2);

    const short8 zf = {0, 0, 0, 0, 0, 0, 0, 0};

    if (!is_grad) {
        // ================= forward (256 samples/block) =================
        const float* X = (bid < nCb) ? C : T;
        float* o1      = (bid < nCb) ? outC : outT;
        const int sb   = ((bid < nCb) ? bid : (bid - nCb)) * BLK;
        const int wb   = 64 * wave;

        short8 xf[4];
#pragma unroll
        for (int st = 0; st < 4; ++st) {
            if (q == 0) {
                const float4* xp = reinterpret_cast<const float4*>(
                    X + (size_t)(sb + wb + 16 * st + c) * NIN);
                xf[st] = pack8(xp[0], xp[1]);
            } else xf[st] = zf;
        }

        // layer 1: products land DIRECTLY in layer-2 A-frag slots
        uint32x4 yf[4][4];
#pragma unroll
        for (int ot = 0; ot < 8; ++ot) {
            short8 wf1 = *reinterpret_cast<const short8*>(wf1p + ot * 256);
            short8 wf2 = *reinterpret_cast<const short8*>(wf2p + ot * 256);
            float4 bi1 = *reinterpret_cast<const float4*>(b11 + 16 * ot + 4 * q);
            float4 bi2 = *reinterpret_cast<const float4*>(b21 + 16 * ot + 4 * q);
            f32x4 c1 = {bi1.x, bi1.y, bi1.z, bi1.w};
            f32x4 c2 = {bi2.x, bi2.y, bi2.z, bi2.w};
#pragma unroll
            for (int st = 0; st < 4; ++st) {
                f32x4 z1 = __builtin_amdgcn_mfma_f32_16x16x32_bf16(wf1, xf[st], c1, 0, 0, 0);
                f32x4 z2 = __builtin_amdgcn_mfma_f32_16x16x32_bf16(wf2, xf[st], c2, 0, 0, 0);
                unsigned u0 = pack_bf16(z1[0] * z2[0], z1[1] * z2[1]);
                unsigned u1 = pack_bf16(z1[2] * z2[2], z1[3] * z2[3]);
                if (ot < 4) { yf[st][ot][0] = u0;     yf[st][ot][1] = u1; }
                else        { yf[st][ot - 4][2] = u0; yf[st][ot - 4][3] = u1; }
            }
        }

        f32x4 g[4] = {{0,0,0,0},{0,0,0,0},{0,0,0,0},{0,0,0,0}};
#pragma unroll 2
        for (int nt = 0; nt < 8; ++nt) {
            int oc = 16 * nt + c;
            short8 bf12[4], bf22[4];
#pragma unroll
            for (int kt = 0; kt < 4; ++kt) {
                int od = oc * 64 + 16 * kt + 4 * q;
                bf12[kt] = *reinterpret_cast<const short8*>(w12p + od);
                bf22[kt] = *reinterpret_cast<const short8*>(w22p + od);
            }
            float bb1 = b12[oc], bb2 = b22[oc], wvv = wout[oc];
#pragma unroll
            for (int mt = 0; mt < 4; ++mt) {
                f32x4 z1 = {bb1, bb1, bb1, bb1};
                f32x4 z2 = {bb2, bb2, bb2, bb2};
#pragma unroll
                for (int kt = 0; kt < 4; ++kt) {
                    short8 af = __builtin_bit_cast(short8, yf[mt][kt]);
                    z1 = __builtin_amdgcn_mfma_f32_16x16x32_bf16(af, bf12[kt], z1, 0, 0, 0);
                    z2 = __builtin_amdgcn_mfma_f32_16x16x32_bf16(af, bf22[kt], z2, 0, 0, 0);
                }
#pragma unroll
                for (int r = 0; r < 4; ++r)
                    g[mt][r] = fmaf(wvv, z1[r] * z2[r], g[mt][r]);
            }
        }
#pragma unroll
        for (int mt = 0; mt < 4; ++mt) {
            float rv[4];
#pragma unroll
            for (int r = 0; r < 4; ++r) {
                float v = g[mt][r];
                v += __shfl_xor(v, 1); v += __shfl_xor(v, 2);
                v += __shfl_xor(v, 4); v += __shfl_xor(v, 8);
                rv[r] = v;
            }
            if (c == 0) {
                int s = sb + wb + 16 * mt + 4 * q;
                *reinterpret_cast<float4*>(&o1[s]) = make_float4(rv[0], rv[1], rv[2], rv[3]);
            }
        }
    } else {
        // ================= forward + JVP (128 samples/block) =================
        const int sb = (bid - nCb - nTb) * (BLK / 2);
        const int wb = 32 * wave;

        short8 xf[2], xdf[2];
#pragma unroll
        for (int st = 0; st < 2; ++st) {
            if (q == 0) {
                size_t s = (size_t)(sb + wb + 16 * st + c) * NIN;
                const float4* xp = reinterpret_cast<const float4*>(L + s);
                const float4* dp = reinterpret_cast<const float4*>(Ld + s);
                xf[st]  = pack8(xp[0], xp[1]);
                xdf[st] = pack8(dp[0], dp[1]);
            } else { xf[st] = zf; xdf[st] = zf; }
        }

        uint32x4 yf[2][4], df[2][4];
        const f32x4 zero4 = {0.f, 0.f, 0.f, 0.f};
#pragma unroll
        for (int ot = 0; ot < 8; ++ot) {
            short8 wf1 = *reinterpret_cast<const short8*>(wf1p + ot * 256);
            short8 wf2 = *reinterpret_cast<const short8*>(wf2p + ot * 256);
            float4 bi1 = *reinterpret_cast<const float4*>(b11 + 16 * ot + 4 * q);
            float4 bi2 = *reinterpret_cast<const float4*>(b21 + 16 * ot + 4 * q);
            f32x4 c1 = {bi1.x, bi1.y, bi1.z, bi1.w};
            f32x4 c2 = {bi2.x, bi2.y, bi2.z, bi2.w};
#pragma unroll
            for (int st = 0; st < 2; ++st) {
                f32x4 z1 = __builtin_amdgcn_mfma_f32_16x16x32_bf16(wf1, xf[st],  c1, 0, 0, 0);
                f32x4 z2 = __builtin_amdgcn_mfma_f32_16x16x32_bf16(wf2, xf[st],  c2, 0, 0, 0);
                f32x4 d1 = __builtin_amdgcn_mfma_f32_16x16x32_bf16(wf1, xdf[st], zero4, 0, 0, 0);
                f32x4 d2 = __builtin_amdgcn_mfma_f32_16x16x32_bf16(wf2, xdf[st], zero4, 0, 0, 0);
                unsigned u0 = pack_bf16(z1[0] * z2[0], z1[1] * z2[1]);
                unsigned u1 = pack_bf16(z1[2] * z2[2], z1[3] * z2[3]);
                // product rule
                unsigned v0 = pack_bf16(d1[0] * z2[0] + z1[0] * d2[0],
                                        d1[1] * z2[1] + z1[1] * d2[1]);
                unsigned v1 = pack_bf16(d1[2] * z2[2] + z1[2] * d2[2],
                                        d1[3] * z2[3] + z1[3] * d2[3]);
                if (ot < 4) {
                    yf[st][ot][0] = u0; yf[st][ot][1] = u1;
                    df[st][ot][0] = v0; df[st][ot][1] = v1;
                } else {
                    yf[st][ot - 4][2] = u0; yf[st][ot - 4][3] = u1;
                    df[st][ot - 4][2] = v0; df[st][ot - 4][3] = v1;
                }
            }
        }

        f32x4 gy[2] = {{0,0,0,0},{0,0,0,0}};
        f32x4 gg[2] = {{0,0,0,0},{0,0,0,0}};
#pragma unroll 2
        for (int nt = 0; nt < 8; ++nt) {
            int oc = 16 * nt + c;
            short8 bf12[4], bf22[4];
#pragma unroll
            for (int kt = 0; kt < 4; ++kt) {
                int od = oc * 64 + 16 * kt + 4 * q;
                bf12[kt] = *reinterpret_cast<const short8*>(w12p + od);
                bf22[kt] = *reinterpret_cast<const short8*>(w22p + od);
            }
            float bb1 = b12[oc], bb2 = b22[oc], wvv = wout[oc];
#pragma unroll
            for (int mt = 0; mt < 2; ++mt) {
                f32x4 z1 = {bb1, bb1, bb1, bb1};
                f32x4 z2 = {bb2, bb2, bb2, bb2};
                f32x4 d1 = {0, 0, 0, 0};
                f32x4 d2 = {0, 0, 0, 0};
#pragma unroll
                for (int kt = 0; kt < 4; ++kt) {
                    short8 af = __builtin_bit_cast(short8, yf[mt][kt]);
                    short8 ad = __builtin_bit_cast(short8, df[mt][kt]);
                    z1 = __builtin_amdgcn_mfma_f32_16x16x32_bf16(af, bf12[kt], z1, 0, 0, 0);
                    z2 = __builtin_amdgcn_mfma_f32_16x16x32_bf16(af, bf22[kt], z2, 0, 0, 0);
                    d1 = __builtin_amdgcn_mfma_f32_16x16x32_bf16(ad, bf12[kt], d1, 0, 0, 0);
                    d2 = __builtin_amdgcn_mfma_f32_16x16x32_bf16(ad, bf22[kt], d2, 0, 0, 0);
                }
#pragma unroll
                for (int r = 0; r < 4; ++r) {
                    gy[mt][r] = fmaf(wvv, z1[r] * z2[r], gy[mt][r]);
                    gg[mt][r] = fmaf(wvv, d1[r] * z2[r] + z1[r] * d2[r], gg[mt][r]);
                }
            }
        }
#pragma unroll
        for (int mt = 0; mt < 2; ++mt) {
            float ry[4], rg[4];
#pragma unroll
            for (int r = 0; r < 4; ++r) {
                float v = gy[mt][r];
                v += __shfl_xor(v, 1); v += __shfl_xor(v, 2);
                v += __shfl_xor(v, 4); v += __shfl_xor(v, 8);
                ry[r] = v;
                float w = gg[mt][r];
                w += __shfl_xor(w, 1); w += __shfl_xor(w, 2);
                w += __shfl_xor(w, 4); w += __shfl_xor(w, 8);
                rg[r] = w;
            }
            if (c == 0) {
                int s = sb + wb + 16 * mt + 4 * q;
                *reinterpret_cast<float4*>(&outY[s]) = make_float4(ry[0], ry[1], ry[2], ry[3]);
                *reinterpret_cast<float4*>(&outG[s]) = make_float4(rg[0], rg[1], rg[2], rg[3]);
            }
        }
    }
}

extern "C" void kernel_launch(void* const* d_in, const int* in_sizes, int n_in,
                              void* d_out, int out_size, void* d_ws, size_t ws_size,
                              hipStream_t stream) {
    const float* T      = (const float*)d_in[0];
    const float* l      = (const float*)d_in[1];
    const float* l1dot  = (const float*)d_in[2];
    const float* center = (const float*)d_in[3];
    const float* w11  = (const float*)d_in[4];
    const float* b11  = (const float*)d_in[5];
    const float* w21  = (const float*)d_in[6];
    const float* b21  = (const float*)d_in[7];
    const float* w12  = (const float*)d_in[8];
    const float* b12  = (const float*)d_in[9];
    const float* w22  = (const float*)d_in[10];
    const float* b22  = (const float*)d_in[11];
    const float* wout = (const float*)d_in[12];

    float* out = (float*)d_out;

    const int nT = in_sizes[0] / NIN;     // 65536
    const int nL = in_sizes[1] / NIN;     // 65536
    const int nC = in_sizes[3] / NIN;     // 512

    conv_w<<<32, 256, 0, stream>>>(w12, w22, w11, w21, (unsigned*)d_ws);

    const int nCb = nC / BLK;             // 2
    const int nTb = nT / BLK;             // 256
    const int nGb = nL / (BLK / 2);       // 512

    net_kernel<<<nCb + nTb + nGb, BLK, 0, stream>>>(
        T, nTb, l, l1dot, center, nCb,
        b11, b21,
        (const unsigned*)d_ws, b12, b22, wout,
        out,                              // v_t
        out + nT,                         // v_y
        out + nT + nL,                    // v_grad
        out + nT + 2 * (size_t)nL);       // v_center
}

// Round 11
// 118.332 us; speedup vs baseline: 1.4071x; 1.4071x over previous
//
#include <hip/hip_runtime.h>
#include <hip/hip_bf16.h>

// Net: x(8) -> SKIP: y = (W11 x + b11)*(W21 x + b21)   (128)
//      -> MUL : y2 = (W12 y + b12)*(W22 y + b22)       (128)
//      -> out = wout . y2                              (scalar)
// grad = JVP with tangent xdot (== reference Jacobian chain . xdot).
//
// R10 postmortem: identity k-permutation hand-off VERIFIED correct (passed,
// conflicts 591K->0, LDS 0) but launch_bounds(256,4) capped VGPR at 128 <
// ~150 live (yf[4][4] uint32x4 = 64 regs alone) -> yf spilled to scratch ->
// WRITE_SIZE 99MB, 90us. R11: launch_bounds(256,2) (cap 256; R9 measured
// 100 under it). No other change. Occupancy floats on real VGPR use
// (<=170 -> 3 waves/SIMD, and no LDS to cap blocks/CU).
//
// Structure: layer-1 MFMA products land DIRECTLY in layer-2 A-frag slots
// because conv_w packs W12/W22 with k(kt,q,j) = 16kt+4q+j (j<4) |
// 64+16kt+4q+(j-4) (j>=4). Zero LDS / barrier / shuffle-transform.
// Layouts HW-verified R7-R10: A/B frag = 4 dwords (16B) per lane,
// C/D col=lane&15, row=4q+r.
//
// d_ws layout (dwords): [0,8192) W12 k-permuted bf16-pairs; [8192,16384)
// W22 same; [16384,18432) W11 A-frags (ot*64+lane)*4; [18432,20480) W21.
//
// Outputs (fp32, concat): v_t[65536], v_y[65536], v_grad[65536], v_center[512]

#define NIN 8
#define H 128
#define BLK 256

typedef short short8 __attribute__((ext_vector_type(8)));
typedef float f32x4 __attribute__((ext_vector_type(4)));
typedef unsigned uint32x4 __attribute__((ext_vector_type(4)));

// fp32 -> bf16 RNE (finite only) — verified R6-R10
__device__ __forceinline__ unsigned bf16_bits(float f) {
    unsigned u = __float_as_uint(f);
    return (u + 0x7fffu + ((u >> 16) & 1u)) >> 16;
}
__device__ __forceinline__ unsigned pack_bf16(float a, float b) {
    return bf16_bits(a) | (bf16_bits(b) << 16);   // a = even element (low 16)
}
__device__ __forceinline__ short8 pack8(float4 a, float4 b) {
    uint4 u = make_uint4(pack_bf16(a.x, a.y), pack_bf16(a.z, a.w),
                         pack_bf16(b.x, b.y), pack_bf16(b.z, b.w));
    return __builtin_bit_cast(short8, u);
}

// Build weight structures in d_ws. B-side (W12/W22) uses the k-permutation
// that makes the layer-1->layer-2 fragment hand-off an identity. (R10-verified)
__global__ __launch_bounds__(256, 1) void conv_w(
    const float* __restrict__ W12, const float* __restrict__ W22,
    const float* __restrict__ W11, const float* __restrict__ W21,
    unsigned* __restrict__ ws)
{
    int i = blockIdx.x * 256 + threadIdx.x;       // 0..8191
    int oc = i >> 6, rem = i & 63;
    int kt = rem >> 4, q = (rem >> 2) & 3, d = rem & 3;
    // dword d of frag (oc,kt,q): j = 2d,2d+1
    int base = (d < 2) ? (16 * kt + 4 * q + 2 * d)
                       : (64 + 16 * kt + 4 * q + 2 * (d - 2));
    const float* r12 = W12 + oc * H;
    const float* r22 = W22 + oc * H;
    ws[i]        = pack_bf16(r12[base], r12[base + 1]);
    ws[8192 + i] = pack_bf16(r22[base], r22[base + 1]);
    if (i < 512) {                                // layer-1 A-frags (R9-verified)
        int ot = i >> 6, lane = i & 63;
        int qq = lane >> 4, c = lane & 15;
        int o = 16 * ot + c;
        uint4 f1 = make_uint4(0, 0, 0, 0), f2 = make_uint4(0, 0, 0, 0);
        if (qq == 0) {                            // k=0..7 real, rest zero
            const float4* r1 = reinterpret_cast<const float4*>(W11 + o * NIN);
            const float4* r2 = reinterpret_cast<const float4*>(W21 + o * NIN);
            float4 x0 = r1[0], x1 = r1[1];
            f1 = make_uint4(pack_bf16(x0.x, x0.y), pack_bf16(x0.z, x0.w),
                            pack_bf16(x1.x, x1.y), pack_bf16(x1.z, x1.w));
            float4 y0 = r2[0], y1 = r2[1];
            f2 = make_uint4(pack_bf16(y0.x, y0.y), pack_bf16(y0.z, y0.w),
                            pack_bf16(y1.x, y1.y), pack_bf16(y1.z, y1.w));
        }
        *reinterpret_cast<uint4*>(ws + 16384 + i * 4) = f1;
        *reinterpret_cast<uint4*>(ws + 18432 + i * 4) = f2;
    }
}

// Blocks: [0,nCb) fwd(center,256); [nCb,nCb+nTb) fwd(T,256); rest grad(l,128).
// NO LDS, NO barrier — waves fully autonomous.
__global__ __launch_bounds__(BLK, 2) void net_kernel(
    const float* __restrict__ T, int nTb,
    const float* __restrict__ L, const float* __restrict__ Ld,
    const float* __restrict__ C, int nCb,
    const float* __restrict__ b11, const float* __restrict__ b21,
    const unsigned* __restrict__ wsb,
    const float* __restrict__ b12, const float* __restrict__ b22,
    const float* __restrict__ wout,
    float* __restrict__ outT, float* __restrict__ outY,
    float* __restrict__ outG, float* __restrict__ outC)
{
    const int tid  = threadIdx.x;
    const int wave = tid >> 6;
    const int lane = tid & 63;
    const int q    = lane >> 4;
    const int c    = lane & 15;

    const int bid = blockIdx.x;
    const bool is_grad = (bid >= nCb + nTb);

    const unsigned* w12p = wsb;
    const unsigned* w22p = wsb + 8192;
    const unsigned* wf1p = wsb + 16384 + (lane << 2);
    const unsigned* wf2p = wsb + 18432 + (lane << 2);

    const short8 zf = {0, 0, 0, 0, 0, 0, 0, 0};

    if (!is_grad) {
        // ================= forward (256 samples/block) =================
        const float* X = (bid < nCb) ? C : T;
        float* o1      = (bid < nCb) ? outC : outT;
        const int sb   = ((bid < nCb) ? bid : (bid - nCb)) * BLK;
        const int wb   = 64 * wave;

        short8 xf[4];
#pragma unroll
        for (int st = 0; st < 4; ++st) {
            if (q == 0) {
                const float4* xp = reinterpret_cast<const float4*>(
                    X + (size_t)(sb + wb + 16 * st + c) * NIN);
                xf[st] = pack8(xp[0], xp[1]);
            } else xf[st] = zf;
        }

        // layer 1: products land DIRECTLY in layer-2 A-frag slots
        uint32x4 yf[4][4];
#pragma unroll
        for (int ot = 0; ot < 8; ++ot) {
            short8 wf1 = *reinterpret_cast<const short8*>(wf1p + ot * 256);
            short8 wf2 = *reinterpret_cast<const short8*>(wf2p + ot * 256);
            float4 bi1 = *reinterpret_cast<const float4*>(b11 + 16 * ot + 4 * q);
            float4 bi2 = *reinterpret_cast<const float4*>(b21 + 16 * ot + 4 * q);
            f32x4 c1 = {bi1.x, bi1.y, bi1.z, bi1.w};
            f32x4 c2 = {bi2.x, bi2.y, bi2.z, bi2.w};
#pragma unroll
            for (int st = 0; st < 4; ++st) {
                f32x4 z1 = __builtin_amdgcn_mfma_f32_16x16x32_bf16(wf1, xf[st], c1, 0, 0, 0);
                f32x4 z2 = __builtin_amdgcn_mfma_f32_16x16x32_bf16(wf2, xf[st], c2, 0, 0, 0);
                unsigned u0 = pack_bf16(z1[0] * z2[0], z1[1] * z2[1]);
                unsigned u1 = pack_bf16(z1[2] * z2[2], z1[3] * z2[3]);
                if (ot < 4) { yf[st][ot][0] = u0;     yf[st][ot][1] = u1; }
                else        { yf[st][ot - 4][2] = u0; yf[st][ot - 4][3] = u1; }
            }
        }

        f32x4 g[4] = {{0,0,0,0},{0,0,0,0},{0,0,0,0},{0,0,0,0}};
#pragma unroll 2
        for (int nt = 0; nt < 8; ++nt) {
            int oc = 16 * nt + c;
            short8 bf12[4], bf22[4];
#pragma unroll
            for (int kt = 0; kt < 4; ++kt) {
                int od = oc * 64 + 16 * kt + 4 * q;
                bf12[kt] = *reinterpret_cast<const short8*>(w12p + od);
                bf22[kt] = *reinterpret_cast<const short8*>(w22p + od);
            }
            float bb1 = b12[oc], bb2 = b22[oc], wvv = wout[oc];
#pragma unroll
            for (int mt = 0; mt < 4; ++mt) {
                f32x4 z1 = {bb1, bb1, bb1, bb1};
                f32x4 z2 = {bb2, bb2, bb2, bb2};
#pragma unroll
                for (int kt = 0; kt < 4; ++kt) {
                    short8 af = __builtin_bit_cast(short8, yf[mt][kt]);
                    z1 = __builtin_amdgcn_mfma_f32_16x16x32_bf16(af, bf12[kt], z1, 0, 0, 0);
                    z2 = __builtin_amdgcn_mfma_f32_16x16x32_bf16(af, bf22[kt], z2, 0, 0, 0);
                }
#pragma unroll
                for (int r = 0; r < 4; ++r)
                    g[mt][r] = fmaf(wvv, z1[r] * z2[r], g[mt][r]);
            }
        }
#pragma unroll
        for (int mt = 0; mt < 4; ++mt) {
            float rv[4];
#pragma unroll
            for (int r = 0; r < 4; ++r) {
                float v = g[mt][r];
                v += __shfl_xor(v, 1); v += __shfl_xor(v, 2);
                v += __shfl_xor(v, 4); v += __shfl_xor(v, 8);
                rv[r] = v;
            }
            if (c == 0) {
                int s = sb + wb + 16 * mt + 4 * q;
                *reinterpret_cast<float4*>(&o1[s]) = make_float4(rv[0], rv[1], rv[2], rv[3]);
            }
        }
    } else {
        // ================= forward + JVP (128 samples/block) =================
        const int sb = (bid - nCb - nTb) * (BLK / 2);
        const int wb = 32 * wave;

        short8 xf[2], xdf[2];
#pragma unroll
        for (int st = 0; st < 2; ++st) {
            if (q == 0) {
                size_t s = (size_t)(sb + wb + 16 * st + c) * NIN;
                const float4* xp = reinterpret_cast<const float4*>(L + s);
                const float4* dp = reinterpret_cast<const float4*>(Ld + s);
                xf[st]  = pack8(xp[0], xp[1]);
                xdf[st] = pack8(dp[0], dp[1]);
            } else { xf[st] = zf; xdf[st] = zf; }
        }

        uint32x4 yf[2][4], df[2][4];
        const f32x4 zero4 = {0.f, 0.f, 0.f, 0.f};
#pragma unroll
        for (int ot = 0; ot < 8; ++ot) {
            short8 wf1 = *reinterpret_cast<const short8*>(wf1p + ot * 256);
            short8 wf2 = *reinterpret_cast<const short8*>(wf2p + ot * 256);
            float4 bi1 = *reinterpret_cast<const float4*>(b11 + 16 * ot + 4 * q);
            float4 bi2 = *reinterpret_cast<const float4*>(b21 + 16 * ot + 4 * q);
            f32x4 c1 = {bi1.x, bi1.y, bi1.z, bi1.w};
            f32x4 c2 = {bi2.x, bi2.y, bi2.z, bi2.w};
#pragma unroll
            for (int st = 0; st < 2; ++st) {
                f32x4 z1 = __builtin_amdgcn_mfma_f32_16x16x32_bf16(wf1, xf[st],  c1, 0, 0, 0);
                f32x4 z2 = __builtin_amdgcn_mfma_f32_16x16x32_bf16(wf2, xf[st],  c2, 0, 0, 0);
                f32x4 d1 = __builtin_amdgcn_mfma_f32_16x16x32_bf16(wf1, xdf[st], zero4, 0, 0, 0);
                f32x4 d2 = __builtin_amdgcn_mfma_f32_16x16x32_bf16(wf2, xdf[st], zero4, 0, 0, 0);
                unsigned u0 = pack_bf16(z1[0] * z2[0], z1[1] * z2[1]);
                unsigned u1 = pack_bf16(z1[2] * z2[2], z1[3] * z2[3]);
                // product rule
                unsigned v0 = pack_bf16(d1[0] * z2[0] + z1[0] * d2[0],
                                        d1[1] * z2[1] + z1[1] * d2[1]);
                unsigned v1 = pack_bf16(d1[2] * z2[2] + z1[2] * d2[2],
                                        d1[3] * z2[3] + z1[3] * d2[3]);
                if (ot < 4) {
                    yf[st][ot][0] = u0; yf[st][ot][1] = u1;
                    df[st][ot][0] = v0; df[st][ot][1] = v1;
                } else {
                    yf[st][ot - 4][2] = u0; yf[st][ot - 4][3] = u1;
                    df[st][ot - 4][2] = v0; df[st][ot - 4][3] = v1;
                }
            }
        }

        f32x4 gy[2] = {{0,0,0,0},{0,0,0,0}};
        f32x4 gg[2] = {{0,0,0,0},{0,0,0,0}};
#pragma unroll 2
        for (int nt = 0; nt < 8; ++nt) {
            int oc = 16 * nt + c;
            short8 bf12[4], bf22[4];
#pragma unroll
            for (int kt = 0; kt < 4; ++kt) {
                int od = oc * 64 + 16 * kt + 4 * q;
                bf12[kt] = *reinterpret_cast<const short8*>(w12p + od);
                bf22[kt] = *reinterpret_cast<const short8*>(w22p + od);
            }
            float bb1 = b12[oc], bb2 = b22[oc], wvv = wout[oc];
#pragma unroll
            for (int mt = 0; mt < 2; ++mt) {
                f32x4 z1 = {bb1, bb1, bb1, bb1};
                f32x4 z2 = {bb2, bb2, bb2, bb2};
                f32x4 d1 = {0, 0, 0, 0};
                f32x4 d2 = {0, 0, 0, 0};
#pragma unroll
                for (int kt = 0; kt < 4; ++kt) {
                    short8 af = __builtin_bit_cast(short8, yf[mt][kt]);
                    short8 ad = __builtin_bit_cast(short8, df[mt][kt]);
                    z1 = __builtin_amdgcn_mfma_f32_16x16x32_bf16(af, bf12[kt], z1, 0, 0, 0);
                    z2 = __builtin_amdgcn_mfma_f32_16x16x32_bf16(af, bf22[kt], z2, 0, 0, 0);
                    d1 = __builtin_amdgcn_mfma_f32_16x16x32_bf16(ad, bf12[kt], d1, 0, 0, 0);
                    d2 = __builtin_amdgcn_mfma_f32_16x16x32_bf16(ad, bf22[kt], d2, 0, 0, 0);
                }
#pragma unroll
                for (int r = 0; r < 4; ++r) {
                    gy[mt][r] = fmaf(wvv, z1[r] * z2[r], gy[mt][r]);
                    gg[mt][r] = fmaf(wvv, d1[r] * z2[r] + z1[r] * d2[r], gg[mt][r]);
                }
            }
        }
#pragma unroll
        for (int mt = 0; mt < 2; ++mt) {
            float ry[4], rg[4];
#pragma unroll
            for (int r = 0; r < 4; ++r) {
                float v = gy[mt][r];
                v += __shfl_xor(v, 1); v += __shfl_xor(v, 2);
                v += __shfl_xor(v, 4); v += __shfl_xor(v, 8);
                ry[r] = v;
                float w = gg[mt][r];
                w += __shfl_xor(w, 1); w += __shfl_xor(w, 2);
                w += __shfl_xor(w, 4); w += __shfl_xor(w, 8);
                rg[r] = w;
            }
            if (c == 0) {
                int s = sb + wb + 16 * mt + 4 * q;
                *reinterpret_cast<float4*>(&outY[s]) = make_float4(ry[0], ry[1], ry[2], ry[3]);
                *reinterpret_cast<float4*>(&outG[s]) = make_float4(rg[0], rg[1], rg[2], rg[3]);
            }
        }
    }
}

extern "C" void kernel_launch(void* const* d_in, const int* in_sizes, int n_in,
                              void* d_out, int out_size, void* d_ws, size_t ws_size,
                              hipStream_t stream) {
    const float* T      = (const float*)d_in[0];
    const float* l      = (const float*)d_in[1];
    const float* l1dot  = (const float*)d_in[2];
    const float* center = (const float*)d_in[3];
    const float* w11  = (const float*)d_in[4];
    const float* b11  = (const float*)d_in[5];
    const float* w21  = (const float*)d_in[6];
    const float* b21  = (const float*)d_in[7];
    const float* w12  = (const float*)d_in[8];
    const float* b12  = (const float*)d_in[9];
    const float* w22  = (const float*)d_in[10];
    const float* b22  = (const float*)d_in[11];
    const float* wout = (const float*)d_in[12];

    float* out = (float*)d_out;

    const int nT = in_sizes[0] / NIN;     // 65536
    const int nL = in_sizes[1] / NIN;     // 65536
    const int nC = in_sizes[3] / NIN;     // 512

    conv_w<<<32, 256, 0, stream>>>(w12, w22, w11, w21, (unsigned*)d_ws);

    const int nCb = nC / BLK;             // 2
    const int nTb = nT / BLK;             // 256
    const int nGb = nL / (BLK / 2);       // 512

    net_kernel<<<nCb + nTb + nGb, BLK, 0, stream>>>(
        T, nTb, l, l1dot, center, nCb,
        b11, b21,
        (const unsigned*)d_ws, b12, b22, wout,
        out,                              // v_t
        out + nT,                         // v_y
        out + nT + nL,                    // v_grad
        out + nT + 2 * (size_t)nL);       // v_center
}

// Round 12
// 107.112 us; speedup vs baseline: 1.5545x; 1.1048x over previous
//
#include <hip/hip_runtime.h>
#include <hip/hip_bf16.h>

// Net: x(8) -> SKIP: y = (W11 x + b11)*(W21 x + b21)   (128)
//      -> MUL : y2 = (W12 y + b12)*(W22 y + b22)       (128)
//      -> out = wout . y2                              (scalar)
// grad = JVP with tangent xdot (== reference Jacobian chain . xdot).
//
// R11 postmortem: R9 (LDS transform) 44.7us vs R11 (no LDS) 42us -> the
// shared bottleneck is per-nt B-frag GATHER loads from global (16 cache
// lines per dwordx4, ~200cyc, 64/wave; only ~160cyc MFMA per unroll-2
// window to hide them). R12: stage W12/W22 frags into LDS once per block,
// FRAG-MAJOR: smem[((nt*4+kt)*4+q)*64 + c*4] -> ds_read_b128 banks (c*4)%32
// = 2-way = free. Staging overlaps layer-1 (pre-barrier). Biases hoisted
// (24 regs; total live ~190 < 256 cap - no spill).
//
// Structure (R10/R11-verified): layer-1 MFMA products land DIRECTLY in
// layer-2 A-frag slots via conv_w's k-permutation k(kt,q,j)=16kt+4q+j (j<4)
// | 64+16kt+4q+(j-4). Layouts HW-verified R7-R11.
//
// d_ws layout (dwords): [0,8192) W12 k-permuted bf16 frags; [8192,16384)
// W22 same; [16384,18432) W11 A-frags (ot*64+lane)*4; [18432,20480) W21.
//
// Outputs (fp32, concat): v_t[65536], v_y[65536], v_grad[65536], v_center[512]

#define NIN 8
#define H 128
#define BLK 256

typedef short short8 __attribute__((ext_vector_type(8)));
typedef float f32x4 __attribute__((ext_vector_type(4)));
typedef unsigned uint32x4 __attribute__((ext_vector_type(4)));

// fp32 -> bf16 RNE (finite only) — verified R6-R11
__device__ __forceinline__ unsigned bf16_bits(float f) {
    unsigned u = __float_as_uint(f);
    return (u + 0x7fffu + ((u >> 16) & 1u)) >> 16;
}
__device__ __forceinline__ unsigned pack_bf16(float a, float b) {
    return bf16_bits(a) | (bf16_bits(b) << 16);   // a = even element (low 16)
}
__device__ __forceinline__ short8 pack8(float4 a, float4 b) {
    uint4 u = make_uint4(pack_bf16(a.x, a.y), pack_bf16(a.z, a.w),
                         pack_bf16(b.x, b.y), pack_bf16(b.z, b.w));
    return __builtin_bit_cast(short8, u);
}

// Build weight structures in d_ws (R10-verified, unchanged).
__global__ __launch_bounds__(256, 1) void conv_w(
    const float* __restrict__ W12, const float* __restrict__ W22,
    const float* __restrict__ W11, const float* __restrict__ W21,
    unsigned* __restrict__ ws)
{
    int i = blockIdx.x * 256 + threadIdx.x;       // 0..8191
    int oc = i >> 6, rem = i & 63;
    int kt = rem >> 4, q = (rem >> 2) & 3, d = rem & 3;
    int base = (d < 2) ? (16 * kt + 4 * q + 2 * d)
                       : (64 + 16 * kt + 4 * q + 2 * (d - 2));
    const float* r12 = W12 + oc * H;
    const float* r22 = W22 + oc * H;
    ws[i]        = pack_bf16(r12[base], r12[base + 1]);
    ws[8192 + i] = pack_bf16(r22[base], r22[base + 1]);
    if (i < 512) {                                // layer-1 A-frags
        int ot = i >> 6, lane = i & 63;
        int qq = lane >> 4, c = lane & 15;
        int o = 16 * ot + c;
        uint4 f1 = make_uint4(0, 0, 0, 0), f2 = make_uint4(0, 0, 0, 0);
        if (qq == 0) {                            // k=0..7 real, rest zero
            const float4* r1 = reinterpret_cast<const float4*>(W11 + o * NIN);
            const float4* r2 = reinterpret_cast<const float4*>(W21 + o * NIN);
            float4 x0 = r1[0], x1 = r1[1];
            f1 = make_uint4(pack_bf16(x0.x, x0.y), pack_bf16(x0.z, x0.w),
                            pack_bf16(x1.x, x1.y), pack_bf16(x1.z, x1.w));
            float4 y0 = r2[0], y1 = r2[1];
            f2 = make_uint4(pack_bf16(y0.x, y0.y), pack_bf16(y0.z, y0.w),
                            pack_bf16(y1.x, y1.y), pack_bf16(y1.z, y1.w));
        }
        *reinterpret_cast<uint4*>(ws + 16384 + i * 4) = f1;
        *reinterpret_cast<uint4*>(ws + 18432 + i * 4) = f2;
    }
}

// Blocks: [0,nCb) fwd(center,256); [nCb,nCb+nTb) fwd(T,256); rest grad(l,128).
__global__ __launch_bounds__(BLK, 2) void net_kernel(
    const float* __restrict__ T, int nTb,
    const float* __restrict__ L, const float* __restrict__ Ld,
    const float* __restrict__ C, int nCb,
    const float* __restrict__ b11, const float* __restrict__ b21,
    const unsigned* __restrict__ wsb,
    const float* __restrict__ b12, const float* __restrict__ b22,
    const float* __restrict__ wout,
    float* __restrict__ outT, float* __restrict__ outY,
    float* __restrict__ outG, float* __restrict__ outC)
{
    // 64 KB: W12 frags [0,8192), W22 frags [8192,16384), frag-major order.
    alignas(16) __shared__ unsigned smem[16384];

    const int tid  = threadIdx.x;
    const int wave = tid >> 6;
    const int lane = tid & 63;
    const int q    = lane >> 4;
    const int c    = lane & 15;

    const int bid = blockIdx.x;
    const bool is_grad = (bid >= nCb + nTb);

    const unsigned* w12p = wsb;
    const unsigned* w22p = wsb + 8192;
    const unsigned* wf1p = wsb + 16384 + (lane << 2);
    const unsigned* wf2p = wsb + 18432 + (lane << 2);

    // ---- stage layer-2 frags global->LDS, frag-major (conflict-free) ----
#pragma unroll
    for (int j = 0; j < 8; ++j) {
        int fid = j * 256 + tid;                  // 0..2047
        int cc = fid & 15, qq = (fid >> 4) & 3;
        int kk = (fid >> 6) & 3, nn = fid >> 8;
        int g = (16 * nn + cc) * 64 + 16 * kk + 4 * qq;   // d_ws frag base
        *reinterpret_cast<uint4*>(&smem[fid * 4]) =
            *reinterpret_cast<const uint4*>(w12p + g);
        *reinterpret_cast<uint4*>(&smem[8192 + fid * 4]) =
            *reinterpret_cast<const uint4*>(w22p + g);
    }

    // ---- hoist layer-2 per-lane constants (loads overlap staging) ----
    float b12v[8], b22v[8], wv[8];
#pragma unroll
    for (int nt = 0; nt < 8; ++nt) {
        b12v[nt] = b12[16 * nt + c];
        b22v[nt] = b22[16 * nt + c];
        wv[nt]   = wout[16 * nt + c];
    }

    const short8 zf = {0, 0, 0, 0, 0, 0, 0, 0};

    if (!is_grad) {
        // ================= forward (256 samples/block) =================
        const float* X = (bid < nCb) ? C : T;
        float* o1      = (bid < nCb) ? outC : outT;
        const int sb   = ((bid < nCb) ? bid : (bid - nCb)) * BLK;
        const int wb   = 64 * wave;

        short8 xf[4];
#pragma unroll
        for (int st = 0; st < 4; ++st) {
            if (q == 0) {
                const float4* xp = reinterpret_cast<const float4*>(
                    X + (size_t)(sb + wb + 16 * st + c) * NIN);
                xf[st] = pack8(xp[0], xp[1]);
            } else xf[st] = zf;
        }

        // layer 1: products land DIRECTLY in layer-2 A-frag slots
        uint32x4 yf[4][4];
#pragma unroll
        for (int ot = 0; ot < 8; ++ot) {
            short8 wf1 = *reinterpret_cast<const short8*>(wf1p + ot * 256);
            short8 wf2 = *reinterpret_cast<const short8*>(wf2p + ot * 256);
            float4 bi1 = *reinterpret_cast<const float4*>(b11 + 16 * ot + 4 * q);
            float4 bi2 = *reinterpret_cast<const float4*>(b21 + 16 * ot + 4 * q);
            f32x4 c1 = {bi1.x, bi1.y, bi1.z, bi1.w};
            f32x4 c2 = {bi2.x, bi2.y, bi2.z, bi2.w};
#pragma unroll
            for (int st = 0; st < 4; ++st) {
                f32x4 z1 = __builtin_amdgcn_mfma_f32_16x16x32_bf16(wf1, xf[st], c1, 0, 0, 0);
                f32x4 z2 = __builtin_amdgcn_mfma_f32_16x16x32_bf16(wf2, xf[st], c2, 0, 0, 0);
                unsigned u0 = pack_bf16(z1[0] * z2[0], z1[1] * z2[1]);
                unsigned u1 = pack_bf16(z1[2] * z2[2], z1[3] * z2[3]);
                if (ot < 4) { yf[st][ot][0] = u0;     yf[st][ot][1] = u1; }
                else        { yf[st][ot - 4][2] = u0; yf[st][ot - 4][3] = u1; }
            }
        }
        __syncthreads();                          // block-uniform path

        f32x4 g[4] = {{0,0,0,0},{0,0,0,0},{0,0,0,0},{0,0,0,0}};
#pragma unroll 2
        for (int nt = 0; nt < 8; ++nt) {
            short8 bf12[4], bf22[4];
#pragma unroll
            for (int kt = 0; kt < 4; ++kt) {
                int lb = nt * 1024 + kt * 256 + q * 64 + c * 4;
                bf12[kt] = *reinterpret_cast<const short8*>(&smem[lb]);
                bf22[kt] = *reinterpret_cast<const short8*>(&smem[8192 + lb]);
            }
            float bb1 = b12v[nt], bb2 = b22v[nt], wvv = wv[nt];
#pragma unroll
            for (int mt = 0; mt < 4; ++mt) {
                f32x4 z1 = {bb1, bb1, bb1, bb1};
                f32x4 z2 = {bb2, bb2, bb2, bb2};
#pragma unroll
                for (int kt = 0; kt < 4; ++kt) {
                    short8 af = __builtin_bit_cast(short8, yf[mt][kt]);
                    z1 = __builtin_amdgcn_mfma_f32_16x16x32_bf16(af, bf12[kt], z1, 0, 0, 0);
                    z2 = __builtin_amdgcn_mfma_f32_16x16x32_bf16(af, bf22[kt], z2, 0, 0, 0);
                }
#pragma unroll
                for (int r = 0; r < 4; ++r)
                    g[mt][r] = fmaf(wvv, z1[r] * z2[r], g[mt][r]);
            }
        }
#pragma unroll
        for (int mt = 0; mt < 4; ++mt) {
            float rv[4];
#pragma unroll
            for (int r = 0; r < 4; ++r) {
                float v = g[mt][r];
                v += __shfl_xor(v, 1); v += __shfl_xor(v, 2);
                v += __shfl_xor(v, 4); v += __shfl_xor(v, 8);
                rv[r] = v;
            }
            if (c == 0) {
                int s = sb + wb + 16 * mt + 4 * q;
                *reinterpret_cast<float4*>(&o1[s]) = make_float4(rv[0], rv[1], rv[2], rv[3]);
            }
        }
    } else {
        // ================= forward + JVP (128 samples/block) =================
        const int sb = (bid - nCb - nTb) * (BLK / 2);
        const int wb = 32 * wave;

        short8 xf[2], xdf[2];
#pragma unroll
        for (int st = 0; st < 2; ++st) {
            if (q == 0) {
                size_t s = (size_t)(sb + wb + 16 * st + c) * NIN;
                const float4* xp = reinterpret_cast<const float4*>(L + s);
                const float4* dp = reinterpret_cast<const float4*>(Ld + s);
                xf[st]  = pack8(xp[0], xp[1]);
                xdf[st] = pack8(dp[0], dp[1]);
            } else { xf[st] = zf; xdf[st] = zf; }
        }

        uint32x4 yf[2][4], df[2][4];
        const f32x4 zero4 = {0.f, 0.f, 0.f, 0.f};
#pragma unroll
        for (int ot = 0; ot < 8; ++ot) {
            short8 wf1 = *reinterpret_cast<const short8*>(wf1p + ot * 256);
            short8 wf2 = *reinterpret_cast<const short8*>(wf2p + ot * 256);
            float4 bi1 = *reinterpret_cast<const float4*>(b11 + 16 * ot + 4 * q);
            float4 bi2 = *reinterpret_cast<const float4*>(b21 + 16 * ot + 4 * q);
            f32x4 c1 = {bi1.x, bi1.y, bi1.z, bi1.w};
            f32x4 c2 = {bi2.x, bi2.y, bi2.z, bi2.w};
#pragma unroll
            for (int st = 0; st < 2; ++st) {
                f32x4 z1 = __builtin_amdgcn_mfma_f32_16x16x32_bf16(wf1, xf[st],  c1, 0, 0, 0);
                f32x4 z2 = __builtin_amdgcn_mfma_f32_16x16x32_bf16(wf2, xf[st],  c2, 0, 0, 0);
                f32x4 d1 = __builtin_amdgcn_mfma_f32_16x16x32_bf16(wf1, xdf[st], zero4, 0, 0, 0);
                f32x4 d2 = __builtin_amdgcn_mfma_f32_16x16x32_bf16(wf2, xdf[st], zero4, 0, 0, 0);
                unsigned u0 = pack_bf16(z1[0] * z2[0], z1[1] * z2[1]);
                unsigned u1 = pack_bf16(z1[2] * z2[2], z1[3] * z2[3]);
                unsigned v0 = pack_bf16(d1[0] * z2[0] + z1[0] * d2[0],
                                        d1[1] * z2[1] + z1[1] * d2[1]);
                unsigned v1 = pack_bf16(d1[2] * z2[2] + z1[2] * d2[2],
                                        d1[3] * z2[3] + z1[3] * d2[3]);
                if (ot < 4) {
                    yf[st][ot][0] = u0; yf[st][ot][1] = u1;
                    df[st][ot][0] = v0; df[st][ot][1] = v1;
                } else {
                    yf[st][ot - 4][2] = u0; yf[st][ot - 4][3] = u1;
                    df[st][ot - 4][2] = v0; df[st][ot - 4][3] = v1;
                }
            }
        }
        __syncthreads();                          // block-uniform path

        f32x4 gy[2] = {{0,0,0,0},{0,0,0,0}};
        f32x4 gg[2] = {{0,0,0,0},{0,0,0,0}};
#pragma unroll 2
        for (int nt = 0; nt < 8; ++nt) {
            short8 bf12[4], bf22[4];
#pragma unroll
            for (int kt = 0; kt < 4; ++kt) {
                int lb = nt * 1024 + kt * 256 + q * 64 + c * 4;
                bf12[kt] = *reinterpret_cast<const short8*>(&smem[lb]);
                bf22[kt] = *reinterpret_cast<const short8*>(&smem[8192 + lb]);
            }
            float bb1 = b12v[nt], bb2 = b22v[nt], wvv = wv[nt];
#pragma unroll
            for (int mt = 0; mt < 2; ++mt) {
                f32x4 z1 = {bb1, bb1, bb1, bb1};
                f32x4 z2 = {bb2, bb2, bb2, bb2};
                f32x4 d1 = {0, 0, 0, 0};
                f32x4 d2 = {0, 0, 0, 0};
#pragma unroll
                for (int kt = 0; kt < 4; ++kt) {
                    short8 af = __builtin_bit_cast(short8, yf[mt][kt]);
                    short8 ad = __builtin_bit_cast(short8, df[mt][kt]);
                    z1 = __builtin_amdgcn_mfma_f32_16x16x32_bf16(af, bf12[kt], z1, 0, 0, 0);
                    z2 = __builtin_amdgcn_mfma_f32_16x16x32_bf16(af, bf22[kt], z2, 0, 0, 0);
                    d1 = __builtin_amdgcn_mfma_f32_16x16x32_bf16(ad, bf12[kt], d1, 0, 0, 0);
                    d2 = __builtin_amdgcn_mfma_f32_16x16x32_bf16(ad, bf22[kt], d2, 0, 0, 0);
                }
#pragma unroll
                for (int r = 0; r < 4; ++r) {
                    gy[mt][r] = fmaf(wvv, z1[r] * z2[r], gy[mt][r]);
                    gg[mt][r] = fmaf(wvv, d1[r] * z2[r] + z1[r] * d2[r], gg[mt][r]);
                }
            }
        }
#pragma unroll
        for (int mt = 0; mt < 2; ++mt) {
            float ry[4], rg[4];
#pragma unroll
            for (int r = 0; r < 4; ++r) {
                float v = gy[mt][r];
                v += __shfl_xor(v, 1); v += __shfl_xor(v, 2);
                v += __shfl_xor(v, 4); v += __shfl_xor(v, 8);
                ry[r] = v;
                float w = gg[mt][r];
                w += __shfl_xor(w, 1); w += __shfl_xor(w, 2);
                w += __shfl_xor(w, 4); w += __shfl_xor(w, 8);
                rg[r] = w;
            }
            if (c == 0) {
                int s = sb + wb + 16 * mt + 4 * q;
                *reinterpret_cast<float4*>(&outY[s]) = make_float4(ry[0], ry[1], ry[2], ry[3]);
                *reinterpret_cast<float4*>(&outG[s]) = make_float4(rg[0], rg[1], rg[2], rg[3]);
            }
        }
    }
}

extern "C" void kernel_launch(void* const* d_in, const int* in_sizes, int n_in,
                              void* d_out, int out_size, void* d_ws, size_t ws_size,
                              hipStream_t stream) {
    const float* T      = (const float*)d_in[0];
    const float* l      = (const float*)d_in[1];
    const float* l1dot  = (const float*)d_in[2];
    const float* center = (const float*)d_in[3];
    const float* w11  = (const float*)d_in[4];
    const float* b11  = (const float*)d_in[5];
    const float* w21  = (const float*)d_in[6];
    const float* b21  = (const float*)d_in[7];
    const float* w12  = (const float*)d_in[8];
    const float* b12  = (const float*)d_in[9];
    const float* w22  = (const float*)d_in[10];
    const float* b22  = (const float*)d_in[11];
    const float* wout = (const float*)d_in[12];

    float* out = (float*)d_out;

    const int nT = in_sizes[0] / NIN;     // 65536
    const int nL = in_sizes[1] / NIN;     // 65536
    const int nC = in_sizes[3] / NIN;     // 512

    conv_w<<<32, 256, 0, stream>>>(w12, w22, w11, w21, (unsigned*)d_ws);

    const int nCb = nC / BLK;             // 2
    const int nTb = nT / BLK;             // 256
    const int nGb = nL / (BLK / 2);       // 512

    net_kernel<<<nCb + nTb + nGb, BLK, 0, stream>>>(
        T, nTb, l, l1dot, center, nCb,
        b11, b21,
        (const unsigned*)d_ws, b12, b22, wout,
        out,                              // v_t
        out + nT,                         // v_y
        out + nT + nL,                    // v_grad
        out + nT + 2 * (size_t)nL);       // v_center
}

// Round 14
// 103.562 us; speedup vs baseline: 1.6077x; 1.0343x over previous
//
#include <hip/hip_runtime.h>
#include <hip/hip_bf16.h>

// Net: x(8) -> SKIP: y = (W11 x + b11)*(W21 x + b21)   (128)
//      -> MUL : y2 = (W12 y + b12)*(W22 y + b22)       (128)
//      -> out = wout . y2                              (scalar)
// grad = JVP with tangent xdot (== reference Jacobian chain . xdot).
//
// R13 postmortem: frag-major design sound, but the kernel's read index used
// wrong strides: fb=(nt*4+kt)*1024+... (4KB per frag-pair) vs conv_w's
// layout f=nt*16+kt*4+q at f*64 dwords -> correct fb = nt*1024 + kt*256 +
// q*64 + c*4 (the exact formula R12's LDS path used). R13 read past the
// 8K-dword W12 region -> garbage B-frags -> absmax 2.5. R14: one-line fix.
//
// Structure (R10-R12-verified): layer-1 MFMA products land DIRECTLY in
// layer-2 A-frag slots via conv_w's k-permutation k(kt,q,j)=16kt+4q+j (j<4)
// | 64+16kt+4q+(j-4). B-frags FRAG-MAJOR in d_ws: wave load = 1KB
// contiguous, L2-resident. No LDS, no barrier. Live ~130 regs < 256 cap.
//
// d_ws layout (dwords): [0,8192) W12 frag-major k-permuted bf16 frags
// (frag (nt,kt,q) at (nt*16+kt*4+q)*64, lane c at +c*4); [8192,16384) W22;
// [16384,18432) W11 A-frags; [18432,20480) W21.
//
// Outputs (fp32, concat): v_t[65536], v_y[65536], v_grad[65536], v_center[512]

#define NIN 8
#define H 128
#define BLK 256

typedef short short8 __attribute__((ext_vector_type(8)));
typedef float f32x4 __attribute__((ext_vector_type(4)));
typedef unsigned uint32x4 __attribute__((ext_vector_type(4)));

// fp32 -> bf16 RNE (finite only) — verified R6-R12
__device__ __forceinline__ unsigned bf16_bits(float f) {
    unsigned u = __float_as_uint(f);
    return (u + 0x7fffu + ((u >> 16) & 1u)) >> 16;
}
__device__ __forceinline__ unsigned pack_bf16(float a, float b) {
    return bf16_bits(a) | (bf16_bits(b) << 16);   // a = even element (low 16)
}
__device__ __forceinline__ short8 pack8(float4 a, float4 b) {
    uint4 u = make_uint4(pack_bf16(a.x, a.y), pack_bf16(a.z, a.w),
                         pack_bf16(b.x, b.y), pack_bf16(b.z, b.w));
    return __builtin_bit_cast(short8, u);
}

// Build weight structures in d_ws. B-side FRAG-MAJOR:
// dword i = f*64 + c*4 + d with f = nt*16 + kt*4 + q; content = k-permuted
// pair (same k-map as R10-R12, so the MFMA dot product is unchanged).
__global__ __launch_bounds__(256, 1) void conv_w(
    const float* __restrict__ W12, const float* __restrict__ W22,
    const float* __restrict__ W11, const float* __restrict__ W21,
    unsigned* __restrict__ ws)
{
    int i = blockIdx.x * 256 + threadIdx.x;       // 0..8191
    int d = i & 3, s = i >> 2;                    // s: lane-slot 0..2047
    int c = s & 15, f = s >> 4;                   // f: frag id 0..127
    int q = f & 3, kt = (f >> 2) & 3, nt = f >> 4;
    int oc = 16 * nt + c;
    int base = (d < 2) ? (16 * kt + 4 * q + 2 * d)
                       : (64 + 16 * kt + 4 * q + 2 * (d - 2));
    const float* r12 = W12 + oc * H;
    const float* r22 = W22 + oc * H;
    ws[i]        = pack_bf16(r12[base], r12[base + 1]);
    ws[8192 + i] = pack_bf16(r22[base], r22[base + 1]);
    if (i < 512) {                                // layer-1 A-frags (R9-verified)
        int ot = i >> 6, lane = i & 63;
        int qq = lane >> 4, cc = lane & 15;
        int o = 16 * ot + cc;
        uint4 f1 = make_uint4(0, 0, 0, 0), f2 = make_uint4(0, 0, 0, 0);
        if (qq == 0) {                            // k=0..7 real, rest zero
            const float4* r1 = reinterpret_cast<const float4*>(W11 + o * NIN);
            const float4* r2 = reinterpret_cast<const float4*>(W21 + o * NIN);
            float4 x0 = r1[0], x1 = r1[1];
            f1 = make_uint4(pack_bf16(x0.x, x0.y), pack_bf16(x0.z, x0.w),
                            pack_bf16(x1.x, x1.y), pack_bf16(x1.z, x1.w));
            float4 y0 = r2[0], y1 = r2[1];
            f2 = make_uint4(pack_bf16(y0.x, y0.y), pack_bf16(y0.z, y0.w),
                            pack_bf16(y1.x, y1.y), pack_bf16(y1.z, y1.w));
        }
        *reinterpret_cast<uint4*>(ws + 16384 + i * 4) = f1;
        *reinterpret_cast<uint4*>(ws + 18432 + i * 4) = f2;
    }
}

// Blocks: [0,nCb) fwd(center,256); [nCb,nCb+nTb) fwd(T,256); rest grad(l,128).
// NO LDS, NO barrier — waves fully autonomous; B-frags coalesced from L2.
__global__ __launch_bounds__(BLK, 2) void net_kernel(
    const float* __restrict__ T, int nTb,
    const float* __restrict__ L, const float* __restrict__ Ld,
    const float* __restrict__ C, int nCb,
    const float* __restrict__ b11, const float* __restrict__ b21,
    const unsigned* __restrict__ wsb,
    const float* __restrict__ b12, const float* __restrict__ b22,
    const float* __restrict__ wout,
    float* __restrict__ outT, float* __restrict__ outY,
    float* __restrict__ outG, float* __restrict__ outC)
{
    const int tid  = threadIdx.x;
    const int wave = tid >> 6;
    const int lane = tid & 63;
    const int q    = lane >> 4;
    const int c    = lane & 15;

    const int bid = blockIdx.x;
    const bool is_grad = (bid >= nCb + nTb);

    const unsigned* w12p = wsb;
    const unsigned* w22p = wsb + 8192;
    const unsigned* wf1p = wsb + 16384 + (lane << 2);
    const unsigned* wf2p = wsb + 18432 + (lane << 2);

    // hoisted layer-2 per-lane constants (24 regs)
    float b12v[8], b22v[8], wv[8];
#pragma unroll
    for (int nt = 0; nt < 8; ++nt) {
        b12v[nt] = b12[16 * nt + c];
        b22v[nt] = b22[16 * nt + c];
        wv[nt]   = wout[16 * nt + c];
    }

    const short8 zf = {0, 0, 0, 0, 0, 0, 0, 0};
    const int fbase = (q << 6) + (c << 2);        // lane offset within a frag block

    if (!is_grad) {
        // ================= forward (256 samples/block) =================
        const float* X = (bid < nCb) ? C : T;
        float* o1      = (bid < nCb) ? outC : outT;
        const int sb   = ((bid < nCb) ? bid : (bid - nCb)) * BLK;
        const int wb   = 64 * wave;

        short8 xf[4];
#pragma unroll
        for (int st = 0; st < 4; ++st) {
            if (q == 0) {
                const float4* xp = reinterpret_cast<const float4*>(
                    X + (size_t)(sb + wb + 16 * st + c) * NIN);
                xf[st] = pack8(xp[0], xp[1]);
            } else xf[st] = zf;
        }

        // layer 1: products land DIRECTLY in layer-2 A-frag slots
        uint32x4 yf[4][4];
#pragma unroll
        for (int ot = 0; ot < 8; ++ot) {
            short8 wf1 = *reinterpret_cast<const short8*>(wf1p + ot * 256);
            short8 wf2 = *reinterpret_cast<const short8*>(wf2p + ot * 256);
            float4 bi1 = *reinterpret_cast<const float4*>(b11 + 16 * ot + 4 * q);
            float4 bi2 = *reinterpret_cast<const float4*>(b21 + 16 * ot + 4 * q);
            f32x4 c1 = {bi1.x, bi1.y, bi1.z, bi1.w};
            f32x4 c2 = {bi2.x, bi2.y, bi2.z, bi2.w};
#pragma unroll
            for (int st = 0; st < 4; ++st) {
                f32x4 z1 = __builtin_amdgcn_mfma_f32_16x16x32_bf16(wf1, xf[st], c1, 0, 0, 0);
                f32x4 z2 = __builtin_amdgcn_mfma_f32_16x16x32_bf16(wf2, xf[st], c2, 0, 0, 0);
                unsigned u0 = pack_bf16(z1[0] * z2[0], z1[1] * z2[1]);
                unsigned u1 = pack_bf16(z1[2] * z2[2], z1[3] * z2[3]);
                if (ot < 4) { yf[st][ot][0] = u0;     yf[st][ot][1] = u1; }
                else        { yf[st][ot - 4][2] = u0; yf[st][ot - 4][3] = u1; }
            }
        }

        f32x4 g[4] = {{0,0,0,0},{0,0,0,0},{0,0,0,0},{0,0,0,0}};
#pragma unroll 2
        for (int nt = 0; nt < 8; ++nt) {
            short8 bf12[4], bf22[4];
#pragma unroll
            for (int kt = 0; kt < 4; ++kt) {
                int fb = nt * 1024 + kt * 256 + fbase;   // FIXED strides (R12's lb)
                bf12[kt] = *reinterpret_cast<const short8*>(w12p + fb);
                bf22[kt] = *reinterpret_cast<const short8*>(w22p + fb);
            }
            float bb1 = b12v[nt], bb2 = b22v[nt], wvv = wv[nt];
#pragma unroll
            for (int mt = 0; mt < 4; ++mt) {
                f32x4 z1 = {bb1, bb1, bb1, bb1};
                f32x4 z2 = {bb2, bb2, bb2, bb2};
#pragma unroll
                for (int kt = 0; kt < 4; ++kt) {
                    short8 af = __builtin_bit_cast(short8, yf[mt][kt]);
                    z1 = __builtin_amdgcn_mfma_f32_16x16x32_bf16(af, bf12[kt], z1, 0, 0, 0);
                    z2 = __builtin_amdgcn_mfma_f32_16x16x32_bf16(af, bf22[kt], z2, 0, 0, 0);
                }
#pragma unroll
                for (int r = 0; r < 4; ++r)
                    g[mt][r] = fmaf(wvv, z1[r] * z2[r], g[mt][r]);
            }
        }
#pragma unroll
        for (int mt = 0; mt < 4; ++mt) {
            float rv[4];
#pragma unroll
            for (int r = 0; r < 4; ++r) {
                float v = g[mt][r];
                v += __shfl_xor(v, 1); v += __shfl_xor(v, 2);
                v += __shfl_xor(v, 4); v += __shfl_xor(v, 8);
                rv[r] = v;
            }
            if (c == 0) {
                int s = sb + wb + 16 * mt + 4 * q;
                *reinterpret_cast<float4*>(&o1[s]) = make_float4(rv[0], rv[1], rv[2], rv[3]);
            }
        }
    } else {
        // ================= forward + JVP (128 samples/block) =================
        const int sb = (bid - nCb - nTb) * (BLK / 2);
        const int wb = 32 * wave;

        short8 xf[2], xdf[2];
#pragma unroll
        for (int st = 0; st < 2; ++st) {
            if (q == 0) {
                size_t s = (size_t)(sb + wb + 16 * st + c) * NIN;
                const float4* xp = reinterpret_cast<const float4*>(L + s);
                const float4* dp = reinterpret_cast<const float4*>(Ld + s);
                xf[st]  = pack8(xp[0], xp[1]);
                xdf[st] = pack8(dp[0], dp[1]);
            } else { xf[st] = zf; xdf[st] = zf; }
        }

        uint32x4 yf[2][4], df[2][4];
        const f32x4 zero4 = {0.f, 0.f, 0.f, 0.f};
#pragma unroll
        for (int ot = 0; ot < 8; ++ot) {
            short8 wf1 = *reinterpret_cast<const short8*>(wf1p + ot * 256);
            short8 wf2 = *reinterpret_cast<const short8*>(wf2p + ot * 256);
            float4 bi1 = *reinterpret_cast<const float4*>(b11 + 16 * ot + 4 * q);
            float4 bi2 = *reinterpret_cast<const float4*>(b21 + 16 * ot + 4 * q);
            f32x4 c1 = {bi1.x, bi1.y, bi1.z, bi1.w};
            f32x4 c2 = {bi2.x, bi2.y, bi2.z, bi2.w};
#pragma unroll
            for (int st = 0; st < 2; ++st) {
                f32x4 z1 = __builtin_amdgcn_mfma_f32_16x16x32_bf16(wf1, xf[st],  c1, 0, 0, 0);
                f32x4 z2 = __builtin_amdgcn_mfma_f32_16x16x32_bf16(wf2, xf[st],  c2, 0, 0, 0);
                f32x4 d1 = __builtin_amdgcn_mfma_f32_16x16x32_bf16(wf1, xdf[st], zero4, 0, 0, 0);
                f32x4 d2 = __builtin_amdgcn_mfma_f32_16x16x32_bf16(wf2, xdf[st], zero4, 0, 0, 0);
                unsigned u0 = pack_bf16(z1[0] * z2[0], z1[1] * z2[1]);
                unsigned u1 = pack_bf16(z1[2] * z2[2], z1[3] * z2[3]);
                // product rule
                unsigned v0 = pack_bf16(d1[0] * z2[0] + z1[0] * d2[0],
                                        d1[1] * z2[1] + z1[1] * d2[1]);
                unsigned v1 = pack_bf16(d1[2] * z2[2] + z1[2] * d2[2],
                                        d1[3] * z2[3] + z1[3] * d2[3]);
                if (ot < 4) {
                    yf[st][ot][0] = u0; yf[st][ot][1] = u1;
                    df[st][ot][0] = v0; df[st][ot][1] = v1;
                } else {
                    yf[st][ot - 4][2] = u0; yf[st][ot - 4][3] = u1;
                    df[st][ot - 4][2] = v0; df[st][ot - 4][3] = v1;
                }
            }
        }

        f32x4 gy[2] = {{0,0,0,0},{0,0,0,0}};
        f32x4 gg[2] = {{0,0,0,0},{0,0,0,0}};
#pragma unroll 2
        for (int nt = 0; nt < 8; ++nt) {
            short8 bf12[4], bf22[4];
#pragma unroll
            for (int kt = 0; kt < 4; ++kt) {
                int fb = nt * 1024 + kt * 256 + fbase;   // FIXED strides (R12's lb)
                bf12[kt] = *reinterpret_cast<const short8*>(w12p + fb);
                bf22[kt] = *reinterpret_cast<const short8*>(w22p + fb);
            }
            float bb1 = b12v[nt], bb2 = b22v[nt], wvv = wv[nt];
#pragma unroll
            for (int mt = 0; mt < 2; ++mt) {
                f32x4 z1 = {bb1, bb1, bb1, bb1};
                f32x4 z2 = {bb2, bb2, bb2, bb2};
                f32x4 d1 = {0, 0, 0, 0};
                f32x4 d2 = {0, 0, 0, 0};
#pragma unroll
                for (int kt = 0; kt < 4; ++kt) {
                    short8 af = __builtin_bit_cast(short8, yf[mt][kt]);
                    short8 ad = __builtin_bit_cast(short8, df[mt][kt]);
                    z1 = __builtin_amdgcn_mfma_f32_16x16x32_bf16(af, bf12[kt], z1, 0, 0, 0);
                    z2 = __builtin_amdgcn_mfma_f32_16x16x32_bf16(af, bf22[kt], z2, 0, 0, 0);
                    d1 = __builtin_amdgcn_mfma_f32_16x16x32_bf16(ad, bf12[kt], d1, 0, 0, 0);
                    d2 = __builtin_amdgcn_mfma_f32_16x16x32_bf16(ad, bf22[kt], d2, 0, 0, 0);
                }
#pragma unroll
                for (int r = 0; r < 4; ++r) {
                    gy[mt][r] = fmaf(wvv, z1[r] * z2[r], gy[mt][r]);
                    gg[mt][r] = fmaf(wvv, d1[r] * z2[r] + z1[r] * d2[r], gg[mt][r]);
                }
            }
        }
#pragma unroll
        for (int mt = 0; mt < 2; ++mt) {
            float ry[4], rg[4];
#pragma unroll
            for (int r = 0; r < 4; ++r) {
                float v = gy[mt][r];
                v += __shfl_xor(v, 1); v += __shfl_xor(v, 2);
                v += __shfl_xor(v, 4); v += __shfl_xor(v, 8);
                ry[r] = v;
                float w = gg[mt][r];
                w += __shfl_xor(w, 1); w += __shfl_xor(w, 2);
                w += __shfl_xor(w, 4); w += __shfl_xor(w, 8);
                rg[r] = w;
            }
            if (c == 0) {
                int s = sb + wb + 16 * mt + 4 * q;
                *reinterpret_cast<float4*>(&outY[s]) = make_float4(ry[0], ry[1], ry[2], ry[3]);
                *reinterpret_cast<float4*>(&outG[s]) = make_float4(rg[0], rg[1], rg[2], rg[3]);
            }
        }
    }
}

extern "C" void kernel_launch(void* const* d_in, const int* in_sizes, int n_in,
                              void* d_out, int out_size, void* d_ws, size_t ws_size,
                              hipStream_t stream) {
    const float* T      = (const float*)d_in[0];
    const float* l      = (const float*)d_in[1];
    const float* l1dot  = (const float*)d_in[2];
    const float* center = (const float*)d_in[3];
    const float* w11  = (const float*)d_in[4];
    const float* b11  = (const float*)d_in[5];
    const float* w21  = (const float*)d_in[6];
    const float* b21  = (const float*)d_in[7];
    const float* w12  = (const float*)d_in[8];
    const float* b12  = (const float*)d_in[9];
    const float* w22  = (const float*)d_in[10];
    const float* b22  = (const float*)d_in[11];
    const float* wout = (const float*)d_in[12];

    float* out = (float*)d_out;

    const int nT = in_sizes[0] / NIN;     // 65536
    const int nL = in_sizes[1] / NIN;     // 65536
    const int nC = in_sizes[3] / NIN;     // 512

    conv_w<<<32, 256, 0, stream>>>(w12, w22, w11, w21, (unsigned*)d_ws);

    const int nCb = nC / BLK;             // 2
    const int nTb = nT / BLK;             // 256
    const int nGb = nL / (BLK / 2);       // 512

    net_kernel<<<nCb + nTb + nGb, BLK, 0, stream>>>(
        T, nTb, l, l1dot, center, nCb,
        b11, b21,
        (const unsigned*)d_ws, b12, b22, wout,
        out,                              // v_t
        out + nT,                         // v_y
        out + nT + nL,                    // v_grad
        out + nT + 2 * (size_t)nL);       // v_center
}